// Round 11
// baseline (131.626 us; speedup 1.0000x reference)
//
#include <hip/hip_runtime.h>
#include <stdint.h>

#define EPS 1e-3f

typedef __bf16 bf16x8 __attribute__((ext_vector_type(8)));
typedef float  f32x4  __attribute__((ext_vector_type(4)));

static __device__ __forceinline__ uint16_t f2bf(float f) {
  union { __bf16 b; uint16_t u; } r; r.b = (__bf16)f; return r.u;
}
static __device__ __forceinline__ uint32_t cvt2(float lo, float hi) {
  union { __bf16 b[2]; uint32_t u; } r;
  r.b[0] = (__bf16)lo; r.b[1] = (__bf16)hi;
  return r.u;
}
static __device__ __forceinline__ float bf2f(uint16_t u) {
  union { uint32_t u; float f; } c; c.u = ((uint32_t)u) << 16; return c.f;
}
static __device__ __forceinline__ void gload_lds16(const void* g, void* l) {
  __builtin_amdgcn_global_load_lds(
      (const __attribute__((address_space(1))) unsigned int*)g,
      (__attribute__((address_space(3))) unsigned int*)l, 16, 0, 0);
}

// ---------------------------------------------------------------------------
// Kernel 0: W transpose/convert prep (tiny).
// ---------------------------------------------------------------------------
__global__ __launch_bounds__(256) void wprep(
    const float* __restrict__ Wq, const float* __restrict__ Wk,
    const float* __restrict__ Wv, uint16_t* __restrict__ WtP)
{
  const int col = blockIdx.x, t = threadIdx.x;
  float val = (col < 64) ? Wq[t * 64 + col]
            : (col < 80) ? Wk[t * 16 + (col - 64)]
                         : Wv[t * 64 + (col - 80)];
  WtP[col * 264 + t] = f2bf(val);
}

// ---------------------------------------------------------------------------
// Kernel 1: MFMA projections + BN + softmax + V-transpose + lam_c partial.
// Q output is now bf16 (consumed as MFMA operand downstream).
// ---------------------------------------------------------------------------
__global__ __launch_bounds__(512) void proj_mfma(
    const float* __restrict__ x, const uint16_t* __restrict__ WtP,
    const float* __restrict__ gq, const float* __restrict__ bq,
    const float* __restrict__ mq, const float* __restrict__ vq,
    const float* __restrict__ gv, const float* __restrict__ bv,
    const float* __restrict__ mv, const float* __restrict__ vvp,
    uint16_t* __restrict__ Qb, uint16_t* __restrict__ VbfT,
    float* __restrict__ part)
{
  __shared__ __align__(16) char smem[143616];   // xA 67584 + Wt 76032
  uint16_t* const xA = (uint16_t*)smem;         // [128][264] bf16
  char* const Wt = smem + 67584;                // [144][264] bf16

  const int t = threadIdx.x;
  const int wid = t >> 6, lane = t & 63;
  const int bid = blockIdx.x;
  const int b = bid >> 3, mc = bid & 7;
  const int r0 = b * 1024 + mc * 128;

#pragma unroll
  for (int i = 0; i < 10; ++i) {
    int off = (i * 512 + t) * 16;
    gload_lds16((const char*)WtP + off, Wt + off);
  }
  {
    const int row = t >> 2, ks0 = (t & 3) * 64;
    const float* src = x + (size_t)(r0 + row) * 256 + ks0;
    uint16_t* dstp = xA + row * 264 + ks0;
#pragma unroll
    for (int i = 0; i < 8; ++i) {
      float4 d0 = *(const float4*)(src + i * 8);
      float4 d1 = *(const float4*)(src + i * 8 + 4);
      uint4 qv;
      qv.x = cvt2(d0.x, d0.y); qv.y = cvt2(d0.z, d0.w);
      qv.z = cvt2(d1.x, d1.y); qv.w = cvt2(d1.z, d1.w);
      *(uint4*)(dstp + i * 8) = qv;
    }
  }
  __syncthreads();

  f32x4 acc[9];
#pragma unroll
  for (int f = 0; f < 9; ++f) acc[f] = f32x4{0.f, 0.f, 0.f, 0.f};
  const int arow = wid * 16 + (lane & 15);
#pragma unroll
  for (int kst = 0; kst < 8; ++kst) {
    const int sb = kst * 64 + ((lane >> 4) << 4);
    bf16x8 af = *(const bf16x8*)((const char*)xA + arow * 528 + sb);
#pragma unroll
    for (int f = 0; f < 9; ++f) {
      const int crow = f * 16 + (lane & 15);
      bf16x8 bfr = *(const bf16x8*)(Wt + crow * 528 + sb);
      acc[f] = __builtin_amdgcn_mfma_f32_16x16x32_bf16(af, bfr, acc[f], 0, 0, 0);
    }
  }

  const int cl = lane & 15;
  const int rbase = wid * 16 + ((lane >> 4) << 2);

  float qs[4], qbb[4], qm[4], vs[4], vb[4], vm[4];
#pragma unroll
  for (int f = 0; f < 4; ++f) {
    const int c = f * 16 + cl;
    qs[f] = gq[c] * rsqrtf(vq[c] + EPS); qbb[f] = bq[c]; qm[f] = mq[c];
    vs[f] = gv[c] * rsqrtf(vvp[c] + EPS); vb[f] = bv[c]; vm[f] = mv[c];
  }
#pragma unroll
  for (int f = 0; f < 4; ++f)
#pragma unroll
    for (int r = 0; r < 4; ++r)
      Qb[(size_t)(r0 + rbase + r) * 64 + f * 16 + cl] =
          f2bf((acc[f][r] - qm[f]) * qs[f] + qbb[f]);
  float ex[4];
#pragma unroll
  for (int r = 0; r < 4; ++r) {
    float kv = acc[4][r];
    float mx = kv;
#pragma unroll
    for (int d = 1; d < 16; d <<= 1) mx = fmaxf(mx, __shfl_xor(mx, d, 64));
    float e = __expf(kv - mx);
    float sm = e;
#pragma unroll
    for (int d = 1; d < 16; d <<= 1) sm += __shfl_xor(sm, d, 64);
    ex[r] = e / sm;
  }
  float vv[4][4];
#pragma unroll
  for (int f = 0; f < 4; ++f)
#pragma unroll
    for (int r = 0; r < 4; ++r)
      vv[f][r] = (acc[5 + f][r] - vm[f]) * vs[f] + vb[f];

  __syncthreads();
  float* const vt = (float*)smem;                   // [128][65] f32
  float* const ks = (float*)(smem + 128 * 65 * 4);  // [128][20] f32
#pragma unroll
  for (int r = 0; r < 4; ++r) ks[(rbase + r) * 20 + cl] = ex[r];
#pragma unroll
  for (int f = 0; f < 4; ++f)
#pragma unroll
    for (int r = 0; r < 4; ++r) vt[(rbase + r) * 65 + f * 16 + cl] = vv[f][r];
  __syncthreads();

  {
    const int v = t & 63, grp = t >> 6;
#pragma unroll
    for (int hh = 0; hh < 2; ++hh) {
      uint4 qv;
      qv.x = cvt2(vt[(grp * 16 + hh * 8 + 0) * 65 + v], vt[(grp * 16 + hh * 8 + 1) * 65 + v]);
      qv.y = cvt2(vt[(grp * 16 + hh * 8 + 2) * 65 + v], vt[(grp * 16 + hh * 8 + 3) * 65 + v]);
      qv.z = cvt2(vt[(grp * 16 + hh * 8 + 4) * 65 + v], vt[(grp * 16 + hh * 8 + 5) * 65 + v]);
      qv.w = cvt2(vt[(grp * 16 + hh * 8 + 6) * 65 + v], vt[(grp * 16 + hh * 8 + 7) * 65 + v]);
      *(uint4*)&VbfT[(size_t)(b * 64 + v) * 1024 + mc * 128 + grp * 16 + hh * 8] = qv;
    }
  }
  {
    const int kq = (t >> 6) & 3, half = t >> 8, v = t & 63;
    const int mbase = half * 64;
    float a0 = 0.f, a1 = 0.f, a2 = 0.f, a3 = 0.f;
#pragma unroll 4
    for (int m = 0; m < 64; ++m) {
      float vvx = vt[(mbase + m) * 65 + v];
      a0 = fmaf(ks[(mbase + m) * 20 + kq * 4 + 0], vvx, a0);
      a1 = fmaf(ks[(mbase + m) * 20 + kq * 4 + 1], vvx, a1);
      a2 = fmaf(ks[(mbase + m) * 20 + kq * 4 + 2], vvx, a2);
      a3 = fmaf(ks[(mbase + m) * 20 + kq * 4 + 3], vvx, a3);
    }
    float* dst = part + ((size_t)(b * 16 + mc * 2 + half) << 10) + (kq * 4) * 64 + v;
    dst[0] = a0; dst[64] = a1; dst[128] = a2; dst[192] = a3;
  }
}

// Kernel 2: reduce 16 partials -> Lc[b][k][v]
__global__ __launch_bounds__(256) void lamc_reduce(const float* __restrict__ part,
                                                   float* __restrict__ Lc)
{
  const int gid = blockIdx.x * 256 + threadIdx.x;
  const int b = gid >> 10, r = gid & 1023;
  const float* p = part + ((size_t)b << 14) + r;
  float s = 0.f;
#pragma unroll
  for (int mc = 0; mc < 16; ++mc) s += p[mc << 10];
  Lc[((size_t)b << 10) + r] = s;
}

// ---------------------------------------------------------------------------
// Kernel 3: fused lambda output via k-first factorization.
//   T[b,h,n,m] = sum_k q[b,h,k,n]*E[n,m,k]      (2.2 GF, K=16 pad 32)
//   out[b,h,n,v] = sum_k q*lam_c  +  sum_m T * v[b,v,m]   (8.6 GF)
// Block = 4 n's, 512 thr (8 waves, wave -> 2 b's). Per 64-m chunk:
//   T' phase: mfma(Em, Qs) -> T bf16 in LDS (rows p=b*16+h*4+nl, packed b64)
//   TV phase: mfma(V_global, T) -> acc[v rows x (h,nl) cols]
// LDS: Qs[4n][64bh][40k] 20480 | Em 2x[4n][64m][40k] 40960 | T[256][144B] 36864
// ---------------------------------------------------------------------------
__global__ __launch_bounds__(512, 1) void lambda_out(
    const float* __restrict__ E,        // [1024 n][1024 m][16 k] f32
    const uint16_t* __restrict__ VbfT,  // [1024 bv][1024 m] bf16
    const uint16_t* __restrict__ Qb,    // [16384 row][64 hk] bf16
    const float* __restrict__ Lc,       // [16 b][16 k][64 v] f32
    float* __restrict__ out)            // [16384][256] f32
{
  __shared__ __align__(16) char smem[98304];
  const int t = threadIdx.x;
  const int wid = t >> 6, lane = t & 63;
  const int l = lane & 15, q = lane >> 4;
  const int n0 = blockIdx.x * 4;
  const int h = l >> 2, nl = l & 3;       // acc column decode (rho = l)

  f32x4 acc[2][4];
#pragma unroll
  for (int bl = 0; bl < 2; ++bl)
#pragma unroll
    for (int vf = 0; vf < 4; ++vf) acc[bl][vf] = f32x4{0.f, 0.f, 0.f, 0.f};

  // ---- prologue: Lc -> LDS (alias over Em+T region) ----
#pragma unroll
  for (int i = 0; i < 8; ++i) {
    int off = (i * 512 + t) * 16;
    gload_lds16((const char*)Lc + off, smem + 20480 + off);
  }
  // Qs stage: [n][bh=b*4+h][40k], k0..15 data, k16..31 zero
  if (t < 256) {
    const int n = t >> 6, bh = t & 63, b = bh >> 2, hh = bh & 3;
    const uint4* src = (const uint4*)(Qb + ((size_t)((b << 10) + n0 + n) << 6) + (hh << 4));
    char* dst = smem + n * 5120 + bh * 80;
    uint4 z = {0, 0, 0, 0};
    uint4 q0 = src[0], q1 = src[1];
    *(uint4*)(dst) = q0; *(uint4*)(dst + 16) = q1;
    *(uint4*)(dst + 32) = z; *(uint4*)(dst + 48) = z;
  }
  __syncthreads();

  // ---- Yc init: acc[v, rho] = sum_k q[b,h,k,n0+nl] * Lc[b][k][v] ----
  {
    const float* LcF = (const float*)(smem + 20480);
#pragma unroll
    for (int bl = 0; bl < 2; ++bl) {
      const int b = wid * 2 + bl;
      float qv[16];
#pragma unroll
      for (int kk = 0; kk < 16; ++kk)
        qv[kk] = bf2f(*(const uint16_t*)(smem + nl * 5120 + (b * 4 + h) * 80 + kk * 2));
#pragma unroll
      for (int vf = 0; vf < 4; ++vf) {
#pragma unroll
        for (int kk = 0; kk < 16; ++kk) {
          const float4 lc = *(const float4*)(LcF + b * 1024 + kk * 64 + vf * 16 + q * 4);
          acc[bl][vf][0] = fmaf(qv[kk], lc.x, acc[bl][vf][0]);
          acc[bl][vf][1] = fmaf(qv[kk], lc.y, acc[bl][vf][1]);
          acc[bl][vf][2] = fmaf(qv[kk], lc.z, acc[bl][vf][2]);
          acc[bl][vf][3] = fmaf(qv[kk], lc.w, acc[bl][vf][3]);
        }
      }
    }
  }
  __syncthreads();   // LcLDS region free now

  // ---- zero Em k16..31 pads (both buffers) + stage Em buf0 (chunk 0) ----
  {
    uint4 z = {0, 0, 0, 0};
    const int buf = t >> 8, rest = t & 255;
    char* dz = smem + 20480 + buf * 20480 + (rest >> 6) * 5120 + (rest & 63) * 80 + 32;
    *(uint4*)(dz) = z; *(uint4*)(dz + 16) = z;
  }
  const int spair = t >> 1, skh = t & 1;
  const int sn = spair >> 6, sm = spair & 63;
  const float* Esrc = E + ((size_t)(n0 + sn) << 14) + ((size_t)sm << 4) + skh * 8;
  {
    float4 f0 = *(const float4*)Esrc, f1 = *(const float4*)(Esrc + 4);
    uint4 w; w.x = cvt2(f0.x, f0.y); w.y = cvt2(f0.z, f0.w);
    w.z = cvt2(f1.x, f1.y); w.w = cvt2(f1.z, f1.w);
    *(uint4*)(smem + 20480 + sn * 5120 + sm * 80 + skh * 16) = w;
  }
  __syncthreads();

  // T'-phase wave mapping: n = wid>>1, bh col-frags 2*(wid&1), +1
  const int n_tp = wid >> 1, cf0 = (wid & 1) * 2;
  const int p0 = cf0 * 64 + (l >> 2) * 16 + (l & 3) * 4 + n_tp;   // T row (cf0)
  const int p1 = p0 + 64;                                          // T row (cf0+1)

  float4 f0a, f0b;   // in-flight E chunk

#pragma unroll 1
  for (int mc = 0; mc < 16; ++mc) {
    const int cur = mc & 1;
    char* EmC = smem + 20480 + cur * 20480;
    char* EmN = smem + 20480 + (cur ^ 1) * 20480;
    if (mc < 15) {   // issue next-chunk E loads early (hide under T'+barrier)
      const float* s = Esrc + ((size_t)(mc + 1) << 10);
      f0a = *(const float4*)s; f0b = *(const float4*)(s + 4);
    }
    // ---- T' phase: T[p][m] = sum_k Em[n][m][k]*Qs[n][k][bh] ----
    {
      bf16x8 bq0 = *(const bf16x8*)(smem + n_tp * 5120 + (cf0 * 16 + l) * 80 + q * 16);
      bf16x8 bq1 = *(const bf16x8*)(smem + n_tp * 5120 + ((cf0 + 1) * 16 + l) * 80 + q * 16);
#pragma unroll
      for (int mf = 0; mf < 4; ++mf) {
        bf16x8 ae = *(const bf16x8*)(EmC + n_tp * 5120 + (mf * 16 + l) * 80 + q * 16);
        f32x4 t0 = __builtin_amdgcn_mfma_f32_16x16x32_bf16(ae, bq0, f32x4{0.f,0.f,0.f,0.f}, 0, 0, 0);
        f32x4 t1 = __builtin_amdgcn_mfma_f32_16x16x32_bf16(ae, bq1, f32x4{0.f,0.f,0.f,0.f}, 0, 0, 0);
        const int c = 2 * mf + (q >> 1);
        uint2 w0; w0.x = cvt2(t0[0], t0[1]); w0.y = cvt2(t0[2], t0[3]);
        uint2 w1; w1.x = cvt2(t1[0], t1[1]); w1.y = cvt2(t1[2], t1[3]);
        *(uint2*)(smem + 61440 + p0 * 144 + (((c) ^ (p0 & 7)) << 4) + ((q & 1) << 3)) = w0;
        *(uint2*)(smem + 61440 + p1 * 144 + (((c) ^ (p1 & 7)) << 4) + ((q & 1) << 3)) = w1;
      }
    }
    __syncthreads();   // T visible
    // ---- TV phase: acc[v, rho] += sum_m V[b,v,m]*T[p=b*16+rho][m] ----
    {
      const size_t m0 = (size_t)mc * 64;
#pragma unroll
      for (int bl = 0; bl < 2; ++bl) {
        const int b = wid * 2 + bl;
        const char* trow = smem + 61440 + (b * 16 + l) * 144;
        const int px = (b * 16 + l) & 7;
#pragma unroll
        for (int kst = 0; kst < 2; ++kst) {
          bf16x8 bT = *(const bf16x8*)(trow + (((kst * 4 + q) ^ px) << 4));
#pragma unroll
          for (int vf = 0; vf < 4; ++vf) {
            const uint16_t* vs = VbfT + (((size_t)(b * 64 + vf * 16 + l)) << 10)
                                 + m0 + kst * 32 + q * 8;
            bf16x8 aV = *(const bf16x8*)vs;
            acc[bl][vf] = __builtin_amdgcn_mfma_f32_16x16x32_bf16(aV, bT, acc[bl][vf], 0, 0, 0);
          }
        }
      }
      if (mc < 15) {   // write next Em (loads drained behind T'+barrier)
        uint4 w; w.x = cvt2(f0a.x, f0a.y); w.y = cvt2(f0a.z, f0a.w);
        w.z = cvt2(f0b.x, f0b.y); w.w = cvt2(f0b.z, f0b.w);
        *(uint4*)(EmN + sn * 5120 + sm * 80 + skh * 16) = w;
      }
    }
    __syncthreads();   // T consumed + Em-next ready
  }

  // ---- epilogue: acc -> out (4 consecutive v per lane -> float4) ----
#pragma unroll
  for (int bl = 0; bl < 2; ++bl) {
    const int b = wid * 2 + bl;
#pragma unroll
    for (int vf = 0; vf < 4; ++vf) {
      float4 o;
      o.x = acc[bl][vf][0]; o.y = acc[bl][vf][1];
      o.z = acc[bl][vf][2]; o.w = acc[bl][vf][3];
      *(float4*)(out + (((size_t)((b << 10) + n0 + nl)) << 8)
                 + (h << 6) + vf * 16 + q * 4) = o;
    }
  }
}

// ---------------------------------------------------------------------------
extern "C" void kernel_launch(void* const* d_in, const int* in_sizes, int n_in,
                              void* d_out, int out_size, void* d_ws, size_t ws_size,
                              hipStream_t stream) {
  const float* x   = (const float*)d_in[0];
  const float* Wq  = (const float*)d_in[1];
  const float* Wk  = (const float*)d_in[2];
  const float* Wv  = (const float*)d_in[3];
  const float* gq  = (const float*)d_in[4];
  const float* bq  = (const float*)d_in[5];
  const float* mq  = (const float*)d_in[6];
  const float* vq  = (const float*)d_in[7];
  const float* gv  = (const float*)d_in[8];
  const float* bv  = (const float*)d_in[9];
  const float* mv  = (const float*)d_in[10];
  const float* vvp = (const float*)d_in[11];
  const float* E   = (const float*)d_in[12];
  float* out = (float*)d_out;

  char* ws = (char*)d_ws;
  uint16_t* VbfT = (uint16_t*)(ws);                             // 2 MB
  uint16_t* Qb   = (uint16_t*)(ws + (size_t)(2 << 20));         // 2 MB
  float*    part = (float*)(ws + (size_t)(4 << 20));            // 1 MB
  float*    Lc   = (float*)(ws + (size_t)(5 << 20));            // 64 KB
  uint16_t* WtP  = (uint16_t*)(ws + (size_t)(5 << 20) + 65536); // 80 KB

  hipLaunchKernelGGL(wprep, dim3(144), dim3(256), 0, stream, Wq, Wk, Wv, WtP);
  hipLaunchKernelGGL(proj_mfma, dim3(128), dim3(512), 0, stream, x, WtP,
                     gq, bq, mq, vq, gv, bv, mv, vvp, Qb, VbfT, part);
  hipLaunchKernelGGL(lamc_reduce, dim3(64), dim3(256), 0, stream, part, Lc);
  hipLaunchKernelGGL(lambda_out, dim3(256), dim3(512), 0, stream, E, VbfT, Qb, Lc, out);
}

// Round 12
// 86.839 us; speedup vs baseline: 1.5157x; 1.5157x over previous
//
#include <hip/hip_runtime.h>
#include <stdint.h>

#define EPS 1e-3f

typedef __bf16 bf16x8 __attribute__((ext_vector_type(8)));
typedef float  f32x4  __attribute__((ext_vector_type(4)));

static __device__ __forceinline__ uint16_t f2bf(float f) {
  union { __bf16 b; uint16_t u; } r; r.b = (__bf16)f; return r.u;
}
static __device__ __forceinline__ uint32_t cvt2(float lo, float hi) {
  union { __bf16 b[2]; uint32_t u; } r;
  r.b[0] = (__bf16)lo; r.b[1] = (__bf16)hi;
  return r.u;
}
static __device__ __forceinline__ void gload_lds16(const void* g, void* l) {
  __builtin_amdgcn_global_load_lds(
      (const __attribute__((address_space(1))) unsigned int*)g,
      (__attribute__((address_space(3))) unsigned int*)l, 16, 0, 0);
}

template <int J0>
static __device__ __forceinline__ void mfma2(const bf16x8* areg, bf16x8 b0,
                                             bf16x8 b1, f32x4 (&acc)[8][4]) {
  __builtin_amdgcn_s_setprio(1);
#pragma unroll
  for (int i = 0; i < 8; ++i)
    acc[i][J0] = __builtin_amdgcn_mfma_f32_16x16x32_bf16(areg[i], b0, acc[i][J0], 0, 0, 0);
#pragma unroll
  for (int i = 0; i < 8; ++i)
    acc[i][J0 + 1] = __builtin_amdgcn_mfma_f32_16x16x32_bf16(areg[i], b1, acc[i][J0 + 1], 0, 0, 0);
  __builtin_amdgcn_s_setprio(0);
}

// ---------------------------------------------------------------------------
// Kernel 0: W transpose/convert prep (tiny).
// ---------------------------------------------------------------------------
__global__ __launch_bounds__(256) void wprep(
    const float* __restrict__ Wq, const float* __restrict__ Wk,
    const float* __restrict__ Wv, uint16_t* __restrict__ WtP)
{
  const int col = blockIdx.x, t = threadIdx.x;
  float val = (col < 64) ? Wq[t * 64 + col]
            : (col < 80) ? Wk[t * 16 + (col - 64)]
                         : Wv[t * 64 + (col - 80)];
  WtP[col * 264 + t] = f2bf(val);
}

// ---------------------------------------------------------------------------
// Kernel 1: E convert+transpose.  E:[n][m][16] f32 -> Ebf:[n*16+k][m] bf16
// ---------------------------------------------------------------------------
__global__ __launch_bounds__(256) void econv(const float* __restrict__ E,
                                             uint16_t* __restrict__ Ebf)
{
  __shared__ uint16_t lds[1024 * 20 + 8];
  const int n = blockIdx.x, t = threadIdx.x;
  const float* En = E + (size_t)n * 16384;
#pragma unroll
  for (int i = 0; i < 16; ++i) {
    int f4 = i * 256 + t;
    float4 d = *(const float4*)(En + (size_t)f4 * 4);
    int m = f4 >> 2, k0 = (f4 & 3) * 4;
    uint2 w; w.x = cvt2(d.x, d.y); w.y = cvt2(d.z, d.w);
    *(uint2*)&lds[m * 20 + k0] = w;
  }
  __syncthreads();
  const int k = t & 15, mg = t >> 4;
  uint16_t* dst = Ebf + (size_t)(n * 16 + k) * 1024 + mg * 64;
  const uint16_t* src = lds + (mg * 64) * 20 + k;
#pragma unroll
  for (int s = 0; s < 8; ++s) {
    union { uint16_t u[8]; uint4 q; } pk;
#pragma unroll
    for (int j = 0; j < 8; ++j) pk.u[j] = src[(s * 8 + j) * 20];
    *(uint4*)(dst + s * 8) = pk.q;
  }
}

// ---------------------------------------------------------------------------
// Kernel 2: MFMA projections + BN + softmax + V-transpose + lam_c partial.
// (R8 256-thread version — 256 blocks, best measured)
// ---------------------------------------------------------------------------
__global__ __launch_bounds__(256) void proj_mfma(
    const float* __restrict__ x, const uint16_t* __restrict__ WtP,
    const float* __restrict__ gq, const float* __restrict__ bq,
    const float* __restrict__ mq, const float* __restrict__ vq,
    const float* __restrict__ gv, const float* __restrict__ bv,
    const float* __restrict__ mv, const float* __restrict__ vvp,
    float* __restrict__ Qf, uint16_t* __restrict__ VbfT,
    float* __restrict__ part)
{
  __shared__ __align__(16) char smem[111616];
  uint16_t* const xA = (uint16_t*)smem;         // [64][264] bf16
  char* const Wt = smem + 33792;                // [144][264] bf16

  const int t = threadIdx.x;
  const int wid = t >> 6, lane = t & 63;
  const int bid = blockIdx.x;
  const int b = bid >> 4, mc = bid & 15;
  const int r0 = b * 1024 + mc * 64;

#pragma unroll
  for (int i = 0; i < 19; ++i) {
    int off = (i * 256 + t) * 16;
    gload_lds16((const char*)WtP + off, Wt + off);
  }
  {
    const int row = t >> 2, ks0 = (t & 3) * 64;
    const float* src = x + (size_t)(r0 + row) * 256 + ks0;
    uint16_t* dstp = xA + row * 264 + ks0;
#pragma unroll
    for (int i = 0; i < 8; ++i) {
      float4 d0 = *(const float4*)(src + i * 8);
      float4 d1 = *(const float4*)(src + i * 8 + 4);
      uint4 q;
      q.x = cvt2(d0.x, d0.y); q.y = cvt2(d0.z, d0.w);
      q.z = cvt2(d1.x, d1.y); q.w = cvt2(d1.z, d1.w);
      *(uint4*)(dstp + i * 8) = q;
    }
  }
  __syncthreads();

  f32x4 acc[9];
#pragma unroll
  for (int f = 0; f < 9; ++f) acc[f] = f32x4{0.f, 0.f, 0.f, 0.f};
  const int arow = wid * 16 + (lane & 15);
#pragma unroll
  for (int kst = 0; kst < 8; ++kst) {
    const int sb = kst * 64 + ((lane >> 4) << 4);
    bf16x8 af = *(const bf16x8*)((const char*)xA + arow * 528 + sb);
#pragma unroll
    for (int f = 0; f < 9; ++f) {
      const int crow = f * 16 + (lane & 15);
      bf16x8 bfr = *(const bf16x8*)(Wt + crow * 528 + sb);
      acc[f] = __builtin_amdgcn_mfma_f32_16x16x32_bf16(af, bfr, acc[f], 0, 0, 0);
    }
  }

  const int cl = lane & 15;
  const int rbase = wid * 16 + ((lane >> 4) << 2);

  float qs[4], qb[4], qm[4], vs[4], vb[4], vm[4];
#pragma unroll
  for (int f = 0; f < 4; ++f) {
    const int c = f * 16 + cl;
    qs[f] = gq[c] * rsqrtf(vq[c] + EPS); qb[f] = bq[c]; qm[f] = mq[c];
    vs[f] = gv[c] * rsqrtf(vvp[c] + EPS); vb[f] = bv[c]; vm[f] = mv[c];
  }
#pragma unroll
  for (int f = 0; f < 4; ++f)
#pragma unroll
    for (int r = 0; r < 4; ++r)
      Qf[(size_t)(r0 + rbase + r) * 64 + f * 16 + cl] =
          (acc[f][r] - qm[f]) * qs[f] + qb[f];
  float ex[4];
#pragma unroll
  for (int r = 0; r < 4; ++r) {
    float kv = acc[4][r];
    float mx = kv;
#pragma unroll
    for (int d = 1; d < 16; d <<= 1) mx = fmaxf(mx, __shfl_xor(mx, d, 64));
    float e = __expf(kv - mx);
    float sm = e;
#pragma unroll
    for (int d = 1; d < 16; d <<= 1) sm += __shfl_xor(sm, d, 64);
    ex[r] = e / sm;
  }
  float vv[4][4];
#pragma unroll
  for (int f = 0; f < 4; ++f)
#pragma unroll
    for (int r = 0; r < 4; ++r)
      vv[f][r] = (acc[5 + f][r] - vm[f]) * vs[f] + vb[f];

  __syncthreads();
  float* const vt = (float*)smem;                 // [64][65] f32
  float* const ks = (float*)(smem + 64 * 65 * 4); // [64][20] f32
#pragma unroll
  for (int r = 0; r < 4; ++r) ks[(rbase + r) * 20 + cl] = ex[r];
#pragma unroll
  for (int f = 0; f < 4; ++f)
#pragma unroll
    for (int r = 0; r < 4; ++r) vt[(rbase + r) * 65 + f * 16 + cl] = vv[f][r];
  __syncthreads();

  {
    const int v = t & 63, grp = t >> 6;
#pragma unroll
    for (int h = 0; h < 2; ++h) {
      uint4 q;
      q.x = cvt2(vt[(grp * 16 + h * 8 + 0) * 65 + v], vt[(grp * 16 + h * 8 + 1) * 65 + v]);
      q.y = cvt2(vt[(grp * 16 + h * 8 + 2) * 65 + v], vt[(grp * 16 + h * 8 + 3) * 65 + v]);
      q.z = cvt2(vt[(grp * 16 + h * 8 + 4) * 65 + v], vt[(grp * 16 + h * 8 + 5) * 65 + v]);
      q.w = cvt2(vt[(grp * 16 + h * 8 + 6) * 65 + v], vt[(grp * 16 + h * 8 + 7) * 65 + v]);
      *(uint4*)&VbfT[(size_t)(b * 64 + v) * 1024 + mc * 64 + grp * 16 + h * 8] = q;
    }
  }
  {
    const int kq = t >> 6, v = t & 63;
    float a0 = 0.f, a1 = 0.f, a2 = 0.f, a3 = 0.f;
#pragma unroll 4
    for (int m = 0; m < 64; ++m) {
      float vvx = vt[m * 65 + v];
      a0 = fmaf(ks[m * 20 + kq * 4 + 0], vvx, a0);
      a1 = fmaf(ks[m * 20 + kq * 4 + 1], vvx, a1);
      a2 = fmaf(ks[m * 20 + kq * 4 + 2], vvx, a2);
      a3 = fmaf(ks[m * 20 + kq * 4 + 3], vvx, a3);
    }
    float* dst = part + ((size_t)(b * 16 + mc) << 10) + (kq * 4) * 64 + v;
    dst[0] = a0; dst[64] = a1; dst[128] = a2; dst[192] = a3;
  }
}

// Kernel 3: reduce 16 partials -> Lc[b][k][v]
__global__ __launch_bounds__(256) void lamc_reduce(const float* __restrict__ part,
                                                   float* __restrict__ Lc)
{
  const int gid = blockIdx.x * 256 + threadIdx.x;
  const int b = gid >> 10, r = gid & 1023;
  const float* p = part + ((size_t)b << 14) + r;
  float s = 0.f;
#pragma unroll
  for (int mc = 0; mc < 16; ++mc) s += p[mc << 10];
  Lc[((size_t)b << 10) + r] = s;
}

// ---------------------------------------------------------------------------
// Kernel 4: GEMM + fused epilogue — 8-PHASE counted-vmcnt schedule (T3+T4).
// 256x256 tile, BK=64, 8 waves (2x4). LDS 128KB: 2 bufs x {A_k0,A_k1,B_k0,
// B_k1} k-half regions of [256 rows][32 k] bf16, swizzle (row>>1)&3.
// Per phase: vmcnt (odd phases, never 0 until tail) -> s_barrier ->
// issue 1 half-tile (2 gload_lds) -> ds_read frags -> 16 MFMA.
// Slot-lifetime-derived schedule; steady vmcnt(10); tail 10/8/4/0.
// ---------------------------------------------------------------------------
__global__ __launch_bounds__(512, 1) void gemm_out(
    const uint16_t* __restrict__ Ebf,   // [16384][1024]
    const uint16_t* __restrict__ VbfT,  // [1024][1024]
    const float* __restrict__ Qf,       // [16384][64]
    const float* __restrict__ Lc,       // [16][16][64]
    float* __restrict__ out)            // [16384][256]
{
  __shared__ __align__(16) char smem[131072];
  const int t = threadIdx.x;
  const int wid = t >> 6, lane = t & 63;
  const int wm = wid >> 2, wn = wid & 3;
  const int bid = blockIdx.x;
  const int xcd = bid & 7, idx = bid >> 3;
  const int rb = xcd * 8 + (idx >> 2);   // 0..63
  const int cb = idx & 3;                // 0..3
  const int row0 = rb * 256, col0 = cb * 256;
  const int n0 = rb * 16;

  // staging thread map: 2 instrs per half-tile; chunk id = row*4 + seg
  const int id0 = t, id1 = 512 + t;
  const int sr0 = id0 >> 2, sg0 = id0 & 3;
  const int sr1 = id1 >> 2, sg1 = id1 & 3;
  const int soff0 = sr0 * 1024 + ((sg0 ^ ((sr0 >> 1) & 3)) << 3);
  const int soff1 = sr1 * 1024 + ((sg1 ^ ((sr1 >> 1) & 3)) << 3);
  const int sdst0 = id0 << 4, sdst1 = id1 << 4;

  const uint16_t* Ab = Ebf + ((size_t)row0 << 10);
  const uint16_t* Bb = VbfT + ((size_t)col0 << 10);

  // LDS region offsets: buf c: A_k0 c*64K+0, A_k1 +16K, B_k0 +32K, B_k1 +48K
#define ISSUE(gbase, kt, h, ldsoff)                                           \
  { gload_lds16((gbase) + soff0 + (kt) * 64 + (h) * 32, smem + (ldsoff) + sdst0); \
    gload_lds16((gbase) + soff1 + (kt) * 64 + (h) * 32, smem + (ldsoff) + sdst1); }
#define BARR() { __builtin_amdgcn_s_barrier(); __builtin_amdgcn_sched_barrier(0); }

  // ds_read chunk byte offsets (within a 16KB half region)
  int aoff[8], boff[4];
#pragma unroll
  for (int i = 0; i < 8; ++i) {
    int r = wm * 128 + i * 16 + (lane & 15);
    aoff[i] = (r * 4 + ((lane >> 4) ^ ((r >> 1) & 3))) << 4;
  }
#pragma unroll
  for (int j = 0; j < 4; ++j) {
    int r = wn * 64 + j * 16 + (lane & 15);
    boff[j] = (r * 4 + ((lane >> 4) ^ ((r >> 1) & 3))) << 4;
  }

  f32x4 acc[8][4];
#pragma unroll
  for (int i = 0; i < 8; ++i)
#pragma unroll
    for (int j = 0; j < 4; ++j) acc[i][j] = f32x4{0.f, 0.f, 0.f, 0.f};

  // ---- prologue: 7 half-tiles (14 loads), stream order = steady state ----
  ISSUE(Ab, 0, 0, 0);              // K0.A_k0
  ISSUE(Bb, 0, 0, 32768);          // K0.B_k0
  ISSUE(Ab, 0, 1, 16384);          // K0.A_k1
  ISSUE(Bb, 0, 1, 49152);          // K0.B_k1
  ISSUE(Ab, 1, 0, 65536);          // K1.A_k0
  ISSUE(Bb, 1, 0, 98304);          // K1.B_k0
  ISSUE(Ab, 1, 1, 81920);          // K1.A_k1

#pragma unroll 1
  for (int it = 0; it < 8; ++it) {
    const int kA = it * 2, kB = kA + 1;
    const bool lastI = (it == 7);
    bf16x8 areg[8], b0, b1;

    // ---- ph1: buf0 kk0, j=0,1 ; issue buf1.B_k1 <- kB ----
    asm volatile("s_waitcnt vmcnt(10)" ::: "memory");
    BARR();
    ISSUE(Bb, kB, 1, 114688);      // 65536+49152
#pragma unroll
    for (int i = 0; i < 8; ++i) areg[i] = *(const bf16x8*)(smem + aoff[i]);
    b0 = *(const bf16x8*)(smem + 32768 + boff[0]);
    b1 = *(const bf16x8*)(smem + 32768 + boff[1]);
    mfma2<0>(areg, b0, b1, acc);
    // ---- ph2: buf0 kk0, j=2,3 ; issue buf0.A_k0 <- kA+2 ----
    BARR();
    if (!lastI) ISSUE(Ab, kA + 2, 0, 0);
    b0 = *(const bf16x8*)(smem + 32768 + boff[2]);
    b1 = *(const bf16x8*)(smem + 32768 + boff[3]);
    mfma2<2>(areg, b0, b1, acc);
    // ---- ph3: buf0 kk1, j=0,1 ; issue buf0.B_k0 <- kA+2 ----
    if (lastI) { asm volatile("s_waitcnt vmcnt(8)" ::: "memory"); }
    else       { asm volatile("s_waitcnt vmcnt(10)" ::: "memory"); }
    BARR();
    if (!lastI) ISSUE(Bb, kA + 2, 0, 32768);
#pragma unroll
    for (int i = 0; i < 8; ++i) areg[i] = *(const bf16x8*)(smem + 16384 + aoff[i]);
    b0 = *(const bf16x8*)(smem + 49152 + boff[0]);
    b1 = *(const bf16x8*)(smem + 49152 + boff[1]);
    mfma2<0>(areg, b0, b1, acc);
    // ---- ph4: buf0 kk1, j=2,3 ; issue buf0.A_k1 <- kA+2 ----
    BARR();
    if (!lastI) ISSUE(Ab, kA + 2, 1, 16384);
    b0 = *(const bf16x8*)(smem + 49152 + boff[2]);
    b1 = *(const bf16x8*)(smem + 49152 + boff[3]);
    mfma2<2>(areg, b0, b1, acc);
    // ---- ph5: buf1 kk0, j=0,1 ; issue buf0.B_k1 <- kA+2 ----
    if (lastI) { asm volatile("s_waitcnt vmcnt(4)" ::: "memory"); }
    else       { asm volatile("s_waitcnt vmcnt(10)" ::: "memory"); }
    BARR();
    if (!lastI) ISSUE(Bb, kA + 2, 1, 49152);
#pragma unroll
    for (int i = 0; i < 8; ++i) areg[i] = *(const bf16x8*)(smem + 65536 + aoff[i]);
    b0 = *(const bf16x8*)(smem + 98304 + boff[0]);
    b1 = *(const bf16x8*)(smem + 98304 + boff[1]);
    mfma2<0>(areg, b0, b1, acc);
    // ---- ph6: buf1 kk0, j=2,3 ; issue buf1.A_k0 <- kB+2 ----
    BARR();
    if (!lastI) ISSUE(Ab, kB + 2, 0, 65536);
    b0 = *(const bf16x8*)(smem + 98304 + boff[2]);
    b1 = *(const bf16x8*)(smem + 98304 + boff[3]);
    mfma2<2>(areg, b0, b1, acc);
    // ---- ph7: buf1 kk1, j=0,1 ; issue buf1.B_k0 <- kB+2 ----
    if (lastI) { asm volatile("s_waitcnt vmcnt(0)" ::: "memory"); }
    else       { asm volatile("s_waitcnt vmcnt(10)" ::: "memory"); }
    BARR();
    if (!lastI) ISSUE(Bb, kB + 2, 0, 98304);
#pragma unroll
    for (int i = 0; i < 8; ++i) areg[i] = *(const bf16x8*)(smem + 81920 + aoff[i]);
    b0 = *(const bf16x8*)(smem + 114688 + boff[0]);
    b1 = *(const bf16x8*)(smem + 114688 + boff[1]);
    mfma2<0>(areg, b0, b1, acc);
    // ---- ph8: buf1 kk1, j=2,3 ; issue buf1.A_k1 <- kB+2 ----
    BARR();
    if (!lastI) ISSUE(Ab, kB + 2, 1, 81920);
    b0 = *(const bf16x8*)(smem + 114688 + boff[2]);
    b1 = *(const bf16x8*)(smem + 114688 + boff[3]);
    mfma2<2>(areg, b0, b1, acc);
  }
  __syncthreads();

  // ---- fused epilogue: 4 phases of 64 rows through LDS, fully unrolled ----
  float* Cs = (float*)smem;        // [64][258]
  const int b0i = cb * 4;
#pragma unroll
  for (int p = 0; p < 4; ++p) {
    if (wm == (p >> 1)) {
#pragma unroll
      for (int il = 0; il < 4; ++il) {
        const int i = ((p & 1) << 2) + il;
#pragma unroll
        for (int j = 0; j < 4; ++j) {
          const int col = wn * 64 + j * 16 + (lane & 15);
          const int bb = b0i + (col >> 6), v = col & 63;
#pragma unroll
          for (int r = 0; r < 4; ++r) {
            const int rl = il * 16 + ((lane >> 4) << 2) + r;
            const int k = rl & 15;
            Cs[rl * 258 + col] = acc[i][j][r] + Lc[(size_t)(((bb << 4) + k) << 6) + v];
          }
        }
      }
    }
    __syncthreads();
    {
      const int v = t & 63;
#pragma unroll
      for (int c = 0; c < 8; ++c) {
        const int combo = (wid << 3) + c;               // 0..63
        const int n_l = combo >> 4;
        const int b_l = (combo >> 2) & 3;
        const int h = combo & 3;
        const int n = n0 + (p << 2) + n_l;
        const int bb = b0i + b_l;
        const float* qp = Qf + (((size_t)(bb << 10) + n) << 6) + (h << 4);
        float sum = 0.f;
#pragma unroll
        for (int k = 0; k < 16; ++k)
          sum = fmaf(qp[k], Cs[((n_l << 4) + k) * 258 + (b_l << 6) + v], sum);
        out[(((size_t)(bb << 10) + n) << 8) + (h << 6) + v] = sum;
      }
    }
    __syncthreads();
  }
#undef ISSUE
#undef BARR
}

// ---------------------------------------------------------------------------
extern "C" void kernel_launch(void* const* d_in, const int* in_sizes, int n_in,
                              void* d_out, int out_size, void* d_ws, size_t ws_size,
                              hipStream_t stream) {
  const float* x   = (const float*)d_in[0];
  const float* Wq  = (const float*)d_in[1];
  const float* Wk  = (const float*)d_in[2];
  const float* Wv  = (const float*)d_in[3];
  const float* gq  = (const float*)d_in[4];
  const float* bq  = (const float*)d_in[5];
  const float* mq  = (const float*)d_in[6];
  const float* vq  = (const float*)d_in[7];
  const float* gv  = (const float*)d_in[8];
  const float* bv  = (const float*)d_in[9];
  const float* mv  = (const float*)d_in[10];
  const float* vvp = (const float*)d_in[11];
  const float* E   = (const float*)d_in[12];
  float* out = (float*)d_out;

  char* ws = (char*)d_ws;
  uint16_t* Ebf  = (uint16_t*)(ws);                          // 32 MB
  uint16_t* VbfT = (uint16_t*)(ws + 33554432);               //  2 MB
  float*    Qf   = (float*)(ws + 35651584);                  //  4 MB
  float*    part = (float*)(ws + 39845888);                  //  1 MB
  float*    Lc   = (float*)(ws + 40894464);                  // 64 KB
  uint16_t* WtP  = (uint16_t*)(ws + 40960000);               // 76 KB

  hipLaunchKernelGGL(wprep, dim3(144), dim3(256), 0, stream, Wq, Wk, Wv, WtP);
  hipLaunchKernelGGL(econv, dim3(1024), dim3(256), 0, stream, E, Ebf);
  hipLaunchKernelGGL(proj_mfma, dim3(256), dim3(256), 0, stream, x, WtP,
                     gq, bq, mq, vq, gv, bv, mv, vvp, Qf, VbfT, part);
  hipLaunchKernelGGL(lamc_reduce, dim3(64), dim3(256), 0, stream, part, Lc);
  hipLaunchKernelGGL(gemm_out, dim3(256), dim3(512), 0, stream, Ebf, VbfT, Qf, Lc, out);
}